// Round 2
// baseline (1544.073 us; speedup 1.0000x reference)
//
#include <hip/hip_runtime.h>

#define B_ 4
#define S_ 2048
#define D_ 1024
#define H_ 16
#define SCALE_ 0.03125f
#define EPS_ 1e-5f
#define NBS_ 8192   // B*S

typedef unsigned short ushort_t;
typedef __attribute__((ext_vector_type(8))) short short8;
typedef __attribute__((ext_vector_type(4))) float floatx4;

__device__ __forceinline__ ushort_t f2bf(float f) {
  union { float f; unsigned u; } v; v.f = f;
  unsigned r = v.u + 0x7fffu + ((v.u >> 16) & 1u);
  return (ushort_t)(r >> 16);
}

__device__ __forceinline__ short8 cvt8(float4 a, float4 b) {
  short8 r;
  r[0] = (short)f2bf(a.x); r[1] = (short)f2bf(a.y);
  r[2] = (short)f2bf(a.z); r[3] = (short)f2bf(a.w);
  r[4] = (short)f2bf(b.x); r[5] = (short)f2bf(b.y);
  r[6] = (short)f2bf(b.z); r[7] = (short)f2bf(b.w);
  return r;
}

// ---------------------------------------------------------------------------
// K1: per-head projection  out[b][h][s][n] = X[b][s][:] . W[h][:,n] + bias[h][n]
// X f32 [B,S,D], W f32 [H,D,64], bias f32 [H,64], out bf16 [B,H,S,64]
// grid (S/16, H, B), block 256 (4 waves). Wave w covers n = w*16..w*16+16.
// ---------------------------------------------------------------------------
__global__ __launch_bounds__(256) void proj_k(
    const float* __restrict__ X, const float* __restrict__ W,
    const float* __restrict__ bias, ushort_t* __restrict__ out)
{
  __shared__ ushort_t wt[64][40];   // [n][kk], 80B row stride (16B aligned)
  const int tid = threadIdx.x;
  const int wv = tid >> 6, lane = tid & 63, quad = lane >> 4, l16 = lane & 15;
  const int s0 = blockIdx.x * 16, h = blockIdx.y, b = blockIdx.z;

  const float* Arow = X + (size_t)(b * S_ + s0 + l16) * D_ + quad * 8;
  const float* Wh = W + (size_t)h * D_ * 64;

  floatx4 acc = {0.f, 0.f, 0.f, 0.f};
  const int kk_s = tid >> 3;        // 0..31
  const int n0 = (tid & 7) * 8;     // 0..56

  for (int k0 = 0; k0 < D_; k0 += 32) {
    __syncthreads();
    const float* wp = Wh + (size_t)(k0 + kk_s) * 64 + n0;
    float4 w0 = *(const float4*)wp;
    float4 w1 = *(const float4*)(wp + 4);
    wt[n0 + 0][kk_s] = f2bf(w0.x); wt[n0 + 1][kk_s] = f2bf(w0.y);
    wt[n0 + 2][kk_s] = f2bf(w0.z); wt[n0 + 3][kk_s] = f2bf(w0.w);
    wt[n0 + 4][kk_s] = f2bf(w1.x); wt[n0 + 5][kk_s] = f2bf(w1.y);
    wt[n0 + 6][kk_s] = f2bf(w1.z); wt[n0 + 7][kk_s] = f2bf(w1.w);
    __syncthreads();
    float4 a0 = *(const float4*)(Arow + k0);
    float4 a1 = *(const float4*)(Arow + k0 + 4);
    short8 a = cvt8(a0, a1);
    short8 bfr = *(const short8*)&wt[wv * 16 + l16][quad * 8];
    acc = __builtin_amdgcn_mfma_f32_16x16x32_bf16(a, bfr, acc, 0, 0, 0);
  }
  const int n = wv * 16 + l16;
  const float bs = bias[h * 64 + n];
  size_t base = ((size_t)(b * H_ + h) * S_ + s0 + quad * 4) * 64 + n;
#pragma unroll
  for (int r = 0; r < 4; ++r)
    out[base + (size_t)r * 64] = f2bf(acc[r] + bs);
}

// ---------------------------------------------------------------------------
// K2: flash attention per (q-tile of 64 rows, h, b). Block 256 = 4 waves,
// wave w owns q rows q0+w*16..+16. Loops 32 K/V tiles of 64 rows.
// q/k/v bf16 [B,H,S,64] -> ao bf16 [B,S,H*64]
// ---------------------------------------------------------------------------
__global__ __launch_bounds__(256) void attn_k(
    const ushort_t* __restrict__ q, const ushort_t* __restrict__ k,
    const ushort_t* __restrict__ v, ushort_t* __restrict__ ao)
{
  __shared__ ushort_t kst[64][72];     // K tile natural [t][dk] (144B rows)
  __shared__ ushort_t vt[64][72];      // V tile transposed [dv][t]
  __shared__ ushort_t pl[4][16][72];   // per-wave P round-trip

  const int tid = threadIdx.x;
  const int wv = tid >> 6, lane = tid & 63, quad = lane >> 4, l16 = lane & 15;
  const int q0 = blockIdx.x * 64, h = blockIdx.y, b = blockIdx.z;
  const size_t bh = (size_t)(b * H_ + h) * S_;

  const ushort_t* qrow = q + (bh + q0 + wv * 16 + l16) * 64;
  short8 aq0 = *(const short8*)(qrow + quad * 8);
  short8 aq1 = *(const short8*)(qrow + 32 + quad * 8);

  floatx4 o[4];
  float m[4], l[4];
#pragma unroll
  for (int cb = 0; cb < 4; ++cb) o[cb] = (floatx4){0.f, 0.f, 0.f, 0.f};
#pragma unroll
  for (int r = 0; r < 4; ++r) { m[r] = -1e30f; l[r] = 0.f; }

  const int srow = tid >> 2, c0 = (tid & 3) * 16;

  for (int t0 = 0; t0 < S_; t0 += 64) {
    __syncthreads();
    {
      const ushort_t* sk = k + (bh + t0 + srow) * 64 + c0;
      short8 r0 = *(const short8*)(sk);
      short8 r1 = *(const short8*)(sk + 8);
      *(short8*)&kst[srow][c0] = r0;
      *(short8*)&kst[srow][c0 + 8] = r1;
      const ushort_t* sv = v + (bh + t0 + srow) * 64 + c0;
      short8 v0 = *(const short8*)(sv);
      short8 v1 = *(const short8*)(sv + 8);
#pragma unroll
      for (int i = 0; i < 8; ++i) vt[c0 + i][srow] = (ushort_t)v0[i];
#pragma unroll
      for (int i = 0; i < 8; ++i) vt[c0 + 8 + i][srow] = (ushort_t)v1[i];
    }
    __syncthreads();

    // S = q . k^T  (16 rows x 64 cols per wave)
    floatx4 sc[4];
#pragma unroll
    for (int cb = 0; cb < 4; ++cb) {
      short8 b0 = *(const short8*)&kst[cb * 16 + l16][quad * 8];
      short8 b1 = *(const short8*)&kst[cb * 16 + l16][32 + quad * 8];
      floatx4 z = {0.f, 0.f, 0.f, 0.f};
      z = __builtin_amdgcn_mfma_f32_16x16x32_bf16(aq0, b0, z, 0, 0, 0);
      z = __builtin_amdgcn_mfma_f32_16x16x32_bf16(aq1, b1, z, 0, 0, 0);
      sc[cb] = z;
    }

    // online softmax (rows are quad-private: row = quad*4+r)
    float mx[4];
#pragma unroll
    for (int r = 0; r < 4; ++r) mx[r] = -1e30f;
#pragma unroll
    for (int cb = 0; cb < 4; ++cb)
#pragma unroll
      for (int r = 0; r < 4; ++r) {
        sc[cb][r] *= SCALE_;
        mx[r] = fmaxf(mx[r], sc[cb][r]);
      }
#pragma unroll
    for (int off = 8; off >= 1; off >>= 1)
#pragma unroll
      for (int r = 0; r < 4; ++r) mx[r] = fmaxf(mx[r], __shfl_xor(mx[r], off));

    float alpha[4], rs[4];
#pragma unroll
    for (int r = 0; r < 4; ++r) {
      float mn = fmaxf(m[r], mx[r]);
      alpha[r] = __expf(m[r] - mn);
      m[r] = mn;
      rs[r] = 0.f;
    }
#pragma unroll
    for (int cb = 0; cb < 4; ++cb)
#pragma unroll
      for (int r = 0; r < 4; ++r) {
        float p = __expf(sc[cb][r] - m[r]);
        sc[cb][r] = p;
        rs[r] += p;
      }
#pragma unroll
    for (int off = 8; off >= 1; off >>= 1)
#pragma unroll
      for (int r = 0; r < 4; ++r) rs[r] += __shfl_xor(rs[r], off);
#pragma unroll
    for (int r = 0; r < 4; ++r) l[r] = l[r] * alpha[r] + rs[r];
#pragma unroll
    for (int cb = 0; cb < 4; ++cb)
#pragma unroll
      for (int r = 0; r < 4; ++r) o[cb][r] *= alpha[r];

    // P: C-layout -> A-layout via per-wave LDS round-trip
#pragma unroll
    for (int cb = 0; cb < 4; ++cb)
#pragma unroll
      for (int r = 0; r < 4; ++r)
        pl[wv][quad * 4 + r][cb * 16 + l16] = f2bf(sc[cb][r]);
    __syncthreads();
    short8 ap0 = *(const short8*)&pl[wv][l16][quad * 8];
    short8 ap1 = *(const short8*)&pl[wv][l16][32 + quad * 8];
#pragma unroll
    for (int cb = 0; cb < 4; ++cb) {
      short8 bv0 = *(const short8*)&vt[cb * 16 + l16][quad * 8];
      short8 bv1 = *(const short8*)&vt[cb * 16 + l16][32 + quad * 8];
      o[cb] = __builtin_amdgcn_mfma_f32_16x16x32_bf16(ap0, bv0, o[cb], 0, 0, 0);
      o[cb] = __builtin_amdgcn_mfma_f32_16x16x32_bf16(ap1, bv1, o[cb], 0, 0, 0);
    }
  }

  // epilogue: divide by l, write concat-head layout [B][S][H*64]
#pragma unroll
  for (int cb = 0; cb < 4; ++cb)
#pragma unroll
    for (int r = 0; r < 4; ++r) {
      float val = o[cb][r] / l[r];
      size_t idx = (size_t)(b * S_ + q0 + wv * 16 + quad * 4 + r) * (H_ * 64)
                   + h * 64 + cb * 16 + l16;
      ao[idx] = f2bf(val);
    }
}

// ---------------------------------------------------------------------------
// K3: out-projection + bias + residual -> y (f32).  y[m][d] = ao[m][:].Wo[:,d]
// ao bf16, Wo f32 [D,D], bo f32, resid f32 (= Q input)
// grid (NBS/16, D/64).
// ---------------------------------------------------------------------------
__global__ __launch_bounds__(256) void oproj_k(
    const ushort_t* __restrict__ ao, const float* __restrict__ Wo,
    const float* __restrict__ bo, const float* __restrict__ resid,
    float* __restrict__ y)
{
  __shared__ ushort_t wt[64][40];
  const int tid = threadIdx.x;
  const int wv = tid >> 6, lane = tid & 63, quad = lane >> 4, l16 = lane & 15;
  const int m0 = blockIdx.x * 16, n0 = blockIdx.y * 64;

  const ushort_t* Arow = ao + (size_t)(m0 + l16) * D_ + quad * 8;
  floatx4 acc = {0.f, 0.f, 0.f, 0.f};
  const int kk_s = tid >> 3, nl0 = (tid & 7) * 8;

  for (int k0 = 0; k0 < D_; k0 += 32) {
    __syncthreads();
    const float* wp = Wo + (size_t)(k0 + kk_s) * D_ + n0 + nl0;
    float4 w0 = *(const float4*)wp;
    float4 w1 = *(const float4*)(wp + 4);
    wt[nl0 + 0][kk_s] = f2bf(w0.x); wt[nl0 + 1][kk_s] = f2bf(w0.y);
    wt[nl0 + 2][kk_s] = f2bf(w0.z); wt[nl0 + 3][kk_s] = f2bf(w0.w);
    wt[nl0 + 4][kk_s] = f2bf(w1.x); wt[nl0 + 5][kk_s] = f2bf(w1.y);
    wt[nl0 + 6][kk_s] = f2bf(w1.z); wt[nl0 + 7][kk_s] = f2bf(w1.w);
    __syncthreads();
    short8 a = *(const short8*)(Arow + k0);
    short8 bfr = *(const short8*)&wt[wv * 16 + l16][quad * 8];
    acc = __builtin_amdgcn_mfma_f32_16x16x32_bf16(a, bfr, acc, 0, 0, 0);
  }
  const int d = n0 + wv * 16 + l16;
  const float bias = bo[d];
#pragma unroll
  for (int r = 0; r < 4; ++r) {
    int row = m0 + quad * 4 + r;
    y[(size_t)row * D_ + d] = acc[r] + bias + resid[(size_t)row * D_ + d];
  }
}

// ---------------------------------------------------------------------------
// K4: per-channel sum / sumsq over 8192 samples.
// ---------------------------------------------------------------------------
__global__ __launch_bounds__(256) void stats_k(
    const float* __restrict__ y, float* __restrict__ s1, float* __restrict__ s2)
{
  const int tid = threadIdx.x;
  const int r0 = blockIdx.x * 32;
  float a[4] = {0.f, 0.f, 0.f, 0.f}, bb[4] = {0.f, 0.f, 0.f, 0.f};
  for (int r = 0; r < 32; ++r) {
    const float* row = y + (size_t)(r0 + r) * D_;
#pragma unroll
    for (int j = 0; j < 4; ++j) {
      float vv = row[tid + j * 256];
      a[j] += vv;
      bb[j] += vv * vv;
    }
  }
#pragma unroll
  for (int j = 0; j < 4; ++j) {
    atomicAdd(&s1[tid + j * 256], a[j]);
    atomicAdd(&s2[tid + j * 256], bb[j]);
  }
}

// ---------------------------------------------------------------------------
// K5: batchnorm affine + 64x64 transpose -> out[b][d][s] (f32)
// ---------------------------------------------------------------------------
__global__ __launch_bounds__(256) void norm_k(
    const float* __restrict__ y, const float* __restrict__ s1,
    const float* __restrict__ s2, const float* __restrict__ gamma,
    const float* __restrict__ beta, float* __restrict__ out)
{
  __shared__ float tile[64][65];
  __shared__ float scl[64], sft[64];
  const int tid = threadIdx.x;
  const int s0 = blockIdx.x * 64, d0 = blockIdx.y * 64, b = blockIdx.z;

  if (tid < 64) {
    int d = d0 + tid;
    float mean = s1[d] * (1.f / (float)NBS_);
    float var = s2[d] * (1.f / (float)NBS_) - mean * mean;
    float rstd = rsqrtf(var + EPS_);
    float g = gamma[d];
    scl[tid] = rstd * g;
    sft[tid] = beta[d] - mean * rstd * g;
  }
  __syncthreads();

  const int si = tid >> 2, dc = (tid & 3) * 16;
  const float* row = y + (size_t)(b * S_ + s0 + si) * D_ + d0 + dc;
#pragma unroll
  for (int j = 0; j < 16; ++j)
    tile[si][dc + j] = row[j] * scl[dc + j] + sft[dc + j];
  __syncthreads();

  const int di = tid >> 2, sg = (tid & 3) * 16;
  float* dst = out + (size_t)(b * D_ + d0 + di) * S_ + s0 + sg;
#pragma unroll
  for (int jj = 0; jj < 4; ++jj) {
    float4 p;
    p.x = tile[sg + jj * 4 + 0][di];
    p.y = tile[sg + jj * 4 + 1][di];
    p.z = tile[sg + jj * 4 + 2][di];
    p.w = tile[sg + jj * 4 + 3][di];
    *(float4*)(dst + jj * 4) = p;
  }
}

// ---------------------------------------------------------------------------
extern "C" void kernel_launch(void* const* d_in, const int* in_sizes, int n_in,
                              void* d_out, int out_size, void* d_ws, size_t ws_size,
                              hipStream_t stream)
{
  (void)in_sizes; (void)n_in; (void)out_size; (void)ws_size;
  const float* Q     = (const float*)d_in[0];
  const float* Kin   = (const float*)d_in[1];
  const float* Vin   = (const float*)d_in[2];
  const float* Wq    = (const float*)d_in[3];
  const float* bq    = (const float*)d_in[4];
  const float* Wk    = (const float*)d_in[5];
  const float* bk    = (const float*)d_in[6];
  const float* Wv    = (const float*)d_in[7];
  const float* bv    = (const float*)d_in[8];
  const float* Wo    = (const float*)d_in[9];
  const float* bo    = (const float*)d_in[10];
  const float* gamma = (const float*)d_in[11];
  const float* beta  = (const float*)d_in[12];
  float* out = (float*)d_out;

  char* ws = (char*)d_ws;
  // layout (bytes): qb 0..16M, kb 16..32M, vb 32..48M, ao 48..64M (all bf16)
  // y (f32, 32MB) reuses 0..32M after attention; stats at 33M (inside dead vb)
  ushort_t* qb = (ushort_t*)(ws);
  ushort_t* kb = (ushort_t*)(ws + (size_t)(16u << 20));
  ushort_t* vb = (ushort_t*)(ws + (size_t)(32u << 20));
  ushort_t* ao = (ushort_t*)(ws + (size_t)(48u << 20));
  float*    y  = (float*)(ws);
  float*    s1 = (float*)(ws + (size_t)(33u << 20));
  float*    s2 = (float*)(ws + (size_t)(33u << 20) + 4096);

  proj_k<<<dim3(128, 16, 4), 256, 0, stream>>>(Q, Wq, bq, qb);
  proj_k<<<dim3(128, 16, 4), 256, 0, stream>>>(Kin, Wk, bk, kb);
  proj_k<<<dim3(128, 16, 4), 256, 0, stream>>>(Vin, Wv, bv, vb);
  attn_k<<<dim3(32, 16, 4), 256, 0, stream>>>(qb, kb, vb, ao);
  oproj_k<<<dim3(512, 16, 1), 256, 0, stream>>>(ao, Wo, bo, Q, y);
  hipMemsetAsync(ws + (size_t)(33u << 20), 0, 8192, stream);
  stats_k<<<256, 256, 0, stream>>>(y, s1, s2);
  norm_k<<<dim3(32, 16, 4), 256, 0, stream>>>(y, s1, s2, gamma, beta, out);
}

// Round 3
// 582.012 us; speedup vs baseline: 2.6530x; 2.6530x over previous
//
#include <hip/hip_runtime.h>

#define B_ 4
#define S_ 2048
#define D_ 1024
#define H_ 16
#define SCALE_ 0.03125f
#define EPS_ 1e-5f
#define NBS_ 8192   // B*S

typedef unsigned short ushort_t;
typedef __attribute__((ext_vector_type(8))) short short8;
typedef __attribute__((ext_vector_type(4))) float floatx4;

__device__ __forceinline__ ushort_t f2bf(float f) {
  union { float f; unsigned u; } v; v.f = f;
  unsigned r = v.u + 0x7fffu + ((v.u >> 16) & 1u);
  return (ushort_t)(r >> 16);
}

__device__ __forceinline__ short8 cvt8(float4 a, float4 b) {
  short8 r;
  r[0] = (short)f2bf(a.x); r[1] = (short)f2bf(a.y);
  r[2] = (short)f2bf(a.z); r[3] = (short)f2bf(a.w);
  r[4] = (short)f2bf(b.x); r[5] = (short)f2bf(b.y);
  r[6] = (short)f2bf(b.z); r[7] = (short)f2bf(b.w);
  return r;
}

// async global->LDS, 16B per lane; lds dest = wave-uniform base + lane*16
__device__ __forceinline__ void gload16(const void* g, void* l) {
  __builtin_amdgcn_global_load_lds(
      (const __attribute__((address_space(1))) unsigned int*)g,
      (__attribute__((address_space(3))) unsigned int*)l, 16, 0, 0);
}

// ---------------------------------------------------------------------------
// cvtx_k: f32 -> bf16 elementwise (8 elems/thread)
// ---------------------------------------------------------------------------
__global__ __launch_bounds__(256) void cvtx_k(const float* __restrict__ src,
                                              ushort_t* __restrict__ dst)
{
  size_t i = ((size_t)blockIdx.x * 256 + threadIdx.x) * 8;
  float4 a = *(const float4*)(src + i);
  float4 b = *(const float4*)(src + i + 4);
  *(short8*)(dst + i) = cvt8(a, b);
}

// ---------------------------------------------------------------------------
// wtr_k: weight transpose f32 -> bf16 N x K (k-contiguous).
// mode 0: src = W[h][d][n] ([H,1024,64]); dst[c=h*64+n][d]. tile (tr=c/64=h, tc=d/64)
// mode 1: src = Wo[c][d] ([1024,1024]);  dst[d][c].        tile (tr=d/64, tc=c/64)
// ---------------------------------------------------------------------------
__global__ __launch_bounds__(256) void wtr_k(const float* __restrict__ src,
                                             ushort_t* __restrict__ dst, int mode)
{
  __shared__ float t[64][65];
  const int tr = blockIdx.x, tc = blockIdx.y;
  const float* sb; int sld;
  if (mode == 0) { sb = src + (size_t)tr * 65536 + (size_t)tc * 64 * 64; sld = 64; }
  else           { sb = src + (size_t)tc * 64 * 1024 + (size_t)tr * 64;  sld = 1024; }
  const int tid = threadIdx.x;
  const int rr = tid >> 2, cs = (tid & 3) * 16;
  const float* p = sb + (size_t)rr * sld + cs;
#pragma unroll
  for (int j = 0; j < 16; ++j) t[rr][cs + j] = p[j];
  __syncthreads();
  ushort_t* dp = dst + (size_t)(tr * 64 + rr) * 1024 + tc * 64 + cs;
#pragma unroll
  for (int j = 0; j < 16; ++j) dp[j] = f2bf(t[cs + j][rr]);
}

// ---------------------------------------------------------------------------
// gemm_proj: C[m][c] = A[m][:] . Bw[c][:]  (A: [8192][1024] bf16 k-contig,
// Bw: [1024][1024] bf16 N x K). Output scattered to [B][H][S][64] + bias[c].
// 128x128 tile, BK=32, 4 waves (2x2 of 64x64), m97-style staging.
// ---------------------------------------------------------------------------
__global__ __launch_bounds__(256) void gemm_proj(
    const ushort_t* __restrict__ A, const ushort_t* __restrict__ Bw,
    const float* __restrict__ bias, ushort_t* __restrict__ outp)
{
  __shared__ ushort_t As[128 * 32];
  __shared__ ushort_t Bs[128 * 32];
  const int tid = threadIdx.x;
  const int wv = tid >> 6, lane = tid & 63, quad = lane >> 4, l16 = lane & 15;
  const int m0 = blockIdx.x * 128, n0 = blockIdx.y * 128;
  const int wm = wv & 1, wn = wv >> 1;
  const int lrow = lane >> 2, lkc = (lane & 3) * 8;

  floatx4 acc[4][4];
#pragma unroll
  for (int i = 0; i < 4; ++i)
#pragma unroll
    for (int j = 0; j < 4; ++j) acc[i][j] = (floatx4){0.f, 0.f, 0.f, 0.f};

  for (int k0 = 0; k0 < 1024; k0 += 32) {
    __syncthreads();
#pragma unroll
    for (int j = 0; j < 2; ++j) {
      const int rb = wv * 32 + j * 16;
      gload16(A + (size_t)(m0 + rb + lrow) * 1024 + k0 + lkc,
              (char*)As + rb * 64);
      gload16(Bw + (size_t)(n0 + rb + lrow) * 1024 + k0 + lkc,
              (char*)Bs + rb * 64);
    }
    __syncthreads();
    short8 af[4], bf[4];
#pragma unroll
    for (int i = 0; i < 4; ++i)
      af[i] = *(const short8*)&As[(wm * 64 + i * 16 + l16) * 32 + quad * 8];
#pragma unroll
    for (int i = 0; i < 4; ++i)
      bf[i] = *(const short8*)&Bs[(wn * 64 + i * 16 + l16) * 32 + quad * 8];
#pragma unroll
    for (int mi = 0; mi < 4; ++mi)
#pragma unroll
      for (int ni = 0; ni < 4; ++ni)
        acc[mi][ni] = __builtin_amdgcn_mfma_f32_16x16x32_bf16(
            af[mi], bf[ni], acc[mi][ni], 0, 0, 0);
  }

  const int b = m0 >> 11;             // 128 | 2048 so tiles never straddle b
  const int sbase = (m0 & 2047) + wm * 64;
#pragma unroll
  for (int ni = 0; ni < 4; ++ni) {
    const int c = n0 + wn * 64 + ni * 16 + l16;
    const int h = c >> 6, nn = c & 63;
    const float bs = bias[c];
    ushort_t* op = outp + (size_t)(b * 16 + h) * 2048 * 64 + nn;
#pragma unroll
    for (int mi = 0; mi < 4; ++mi)
#pragma unroll
      for (int r = 0; r < 4; ++r) {
        int s = sbase + mi * 16 + quad * 4 + r;
        op[(size_t)s * 64] = f2bf(acc[mi][ni][r] + bs);
      }
  }
}

// ---------------------------------------------------------------------------
// gemm_oproj: y[m][d] = ao[m][:].Wt_o[d][:] + bo[d] + resid[m][d]  (f32 out)
// ---------------------------------------------------------------------------
__global__ __launch_bounds__(256) void gemm_oproj(
    const ushort_t* __restrict__ A, const ushort_t* __restrict__ Bw,
    const float* __restrict__ bo, const float* __restrict__ resid,
    float* __restrict__ y)
{
  __shared__ ushort_t As[128 * 32];
  __shared__ ushort_t Bs[128 * 32];
  const int tid = threadIdx.x;
  const int wv = tid >> 6, lane = tid & 63, quad = lane >> 4, l16 = lane & 15;
  const int m0 = blockIdx.x * 128, n0 = blockIdx.y * 128;
  const int wm = wv & 1, wn = wv >> 1;
  const int lrow = lane >> 2, lkc = (lane & 3) * 8;

  floatx4 acc[4][4];
#pragma unroll
  for (int i = 0; i < 4; ++i)
#pragma unroll
    for (int j = 0; j < 4; ++j) acc[i][j] = (floatx4){0.f, 0.f, 0.f, 0.f};

  for (int k0 = 0; k0 < 1024; k0 += 32) {
    __syncthreads();
#pragma unroll
    for (int j = 0; j < 2; ++j) {
      const int rb = wv * 32 + j * 16;
      gload16(A + (size_t)(m0 + rb + lrow) * 1024 + k0 + lkc,
              (char*)As + rb * 64);
      gload16(Bw + (size_t)(n0 + rb + lrow) * 1024 + k0 + lkc,
              (char*)Bs + rb * 64);
    }
    __syncthreads();
    short8 af[4], bf[4];
#pragma unroll
    for (int i = 0; i < 4; ++i)
      af[i] = *(const short8*)&As[(wm * 64 + i * 16 + l16) * 32 + quad * 8];
#pragma unroll
    for (int i = 0; i < 4; ++i)
      bf[i] = *(const short8*)&Bs[(wn * 64 + i * 16 + l16) * 32 + quad * 8];
#pragma unroll
    for (int mi = 0; mi < 4; ++mi)
#pragma unroll
      for (int ni = 0; ni < 4; ++ni)
        acc[mi][ni] = __builtin_amdgcn_mfma_f32_16x16x32_bf16(
            af[mi], bf[ni], acc[mi][ni], 0, 0, 0);
  }

  const int mb = m0 + wm * 64;
#pragma unroll
  for (int ni = 0; ni < 4; ++ni) {
    const int d = n0 + wn * 64 + ni * 16 + l16;
    const float bs = bo[d];
#pragma unroll
    for (int mi = 0; mi < 4; ++mi)
#pragma unroll
      for (int r = 0; r < 4; ++r) {
        int m = mb + mi * 16 + quad * 4 + r;
        y[(size_t)m * 1024 + d] = acc[mi][ni][r] + bs + resid[(size_t)m * 1024 + d];
      }
  }
}

// ---------------------------------------------------------------------------
// K2: flash attention (unchanged from passing round)
// ---------------------------------------------------------------------------
__global__ __launch_bounds__(256) void attn_k(
    const ushort_t* __restrict__ q, const ushort_t* __restrict__ k,
    const ushort_t* __restrict__ v, ushort_t* __restrict__ ao)
{
  __shared__ ushort_t kst[64][72];
  __shared__ ushort_t vt[64][72];
  __shared__ ushort_t pl[4][16][72];

  const int tid = threadIdx.x;
  const int wv = tid >> 6, lane = tid & 63, quad = lane >> 4, l16 = lane & 15;
  const int q0 = blockIdx.x * 64, h = blockIdx.y, b = blockIdx.z;
  const size_t bh = (size_t)(b * H_ + h) * S_;

  const ushort_t* qrow = q + (bh + q0 + wv * 16 + l16) * 64;
  short8 aq0 = *(const short8*)(qrow + quad * 8);
  short8 aq1 = *(const short8*)(qrow + 32 + quad * 8);

  floatx4 o[4];
  float m[4], l[4];
#pragma unroll
  for (int cb = 0; cb < 4; ++cb) o[cb] = (floatx4){0.f, 0.f, 0.f, 0.f};
#pragma unroll
  for (int r = 0; r < 4; ++r) { m[r] = -1e30f; l[r] = 0.f; }

  const int srow = tid >> 2, c0 = (tid & 3) * 16;

  for (int t0 = 0; t0 < S_; t0 += 64) {
    __syncthreads();
    {
      const ushort_t* sk = k + (bh + t0 + srow) * 64 + c0;
      short8 r0 = *(const short8*)(sk);
      short8 r1 = *(const short8*)(sk + 8);
      *(short8*)&kst[srow][c0] = r0;
      *(short8*)&kst[srow][c0 + 8] = r1;
      const ushort_t* sv = v + (bh + t0 + srow) * 64 + c0;
      short8 v0 = *(const short8*)(sv);
      short8 v1 = *(const short8*)(sv + 8);
#pragma unroll
      for (int i = 0; i < 8; ++i) vt[c0 + i][srow] = (ushort_t)v0[i];
#pragma unroll
      for (int i = 0; i < 8; ++i) vt[c0 + 8 + i][srow] = (ushort_t)v1[i];
    }
    __syncthreads();

    floatx4 sc[4];
#pragma unroll
    for (int cb = 0; cb < 4; ++cb) {
      short8 b0 = *(const short8*)&kst[cb * 16 + l16][quad * 8];
      short8 b1 = *(const short8*)&kst[cb * 16 + l16][32 + quad * 8];
      floatx4 z = {0.f, 0.f, 0.f, 0.f};
      z = __builtin_amdgcn_mfma_f32_16x16x32_bf16(aq0, b0, z, 0, 0, 0);
      z = __builtin_amdgcn_mfma_f32_16x16x32_bf16(aq1, b1, z, 0, 0, 0);
      sc[cb] = z;
    }

    float mx[4];
#pragma unroll
    for (int r = 0; r < 4; ++r) mx[r] = -1e30f;
#pragma unroll
    for (int cb = 0; cb < 4; ++cb)
#pragma unroll
      for (int r = 0; r < 4; ++r) {
        sc[cb][r] *= SCALE_;
        mx[r] = fmaxf(mx[r], sc[cb][r]);
      }
#pragma unroll
    for (int off = 8; off >= 1; off >>= 1)
#pragma unroll
      for (int r = 0; r < 4; ++r) mx[r] = fmaxf(mx[r], __shfl_xor(mx[r], off));

    float alpha[4], rs[4];
#pragma unroll
    for (int r = 0; r < 4; ++r) {
      float mn = fmaxf(m[r], mx[r]);
      alpha[r] = __expf(m[r] - mn);
      m[r] = mn;
      rs[r] = 0.f;
    }
#pragma unroll
    for (int cb = 0; cb < 4; ++cb)
#pragma unroll
      for (int r = 0; r < 4; ++r) {
        float p = __expf(sc[cb][r] - m[r]);
        sc[cb][r] = p;
        rs[r] += p;
      }
#pragma unroll
    for (int off = 8; off >= 1; off >>= 1)
#pragma unroll
      for (int r = 0; r < 4; ++r) rs[r] += __shfl_xor(rs[r], off);
#pragma unroll
    for (int r = 0; r < 4; ++r) l[r] = l[r] * alpha[r] + rs[r];
#pragma unroll
    for (int cb = 0; cb < 4; ++cb)
#pragma unroll
      for (int r = 0; r < 4; ++r) o[cb][r] *= alpha[r];

#pragma unroll
    for (int cb = 0; cb < 4; ++cb)
#pragma unroll
      for (int r = 0; r < 4; ++r)
        pl[wv][quad * 4 + r][cb * 16 + l16] = f2bf(sc[cb][r]);
    __syncthreads();
    short8 ap0 = *(const short8*)&pl[wv][l16][quad * 8];
    short8 ap1 = *(const short8*)&pl[wv][l16][32 + quad * 8];
#pragma unroll
    for (int cb = 0; cb < 4; ++cb) {
      short8 bv0 = *(const short8*)&vt[cb * 16 + l16][quad * 8];
      short8 bv1 = *(const short8*)&vt[cb * 16 + l16][32 + quad * 8];
      o[cb] = __builtin_amdgcn_mfma_f32_16x16x32_bf16(ap0, bv0, o[cb], 0, 0, 0);
      o[cb] = __builtin_amdgcn_mfma_f32_16x16x32_bf16(ap1, bv1, o[cb], 0, 0, 0);
    }
  }

#pragma unroll
  for (int cb = 0; cb < 4; ++cb)
#pragma unroll
    for (int r = 0; r < 4; ++r) {
      float val = o[cb][r] / l[r];
      size_t idx = (size_t)(b * S_ + q0 + wv * 16 + quad * 4 + r) * (H_ * 64)
                   + h * 64 + cb * 16 + l16;
      ao[idx] = f2bf(val);
    }
}

// ---------------------------------------------------------------------------
// K4: per-channel sum / sumsq over 8192 samples.
// ---------------------------------------------------------------------------
__global__ __launch_bounds__(256) void stats_k(
    const float* __restrict__ y, float* __restrict__ s1, float* __restrict__ s2)
{
  const int tid = threadIdx.x;
  const int r0 = blockIdx.x * 32;
  float a[4] = {0.f, 0.f, 0.f, 0.f}, bb[4] = {0.f, 0.f, 0.f, 0.f};
  for (int r = 0; r < 32; ++r) {
    const float* row = y + (size_t)(r0 + r) * D_;
#pragma unroll
    for (int j = 0; j < 4; ++j) {
      float vv = row[tid + j * 256];
      a[j] += vv;
      bb[j] += vv * vv;
    }
  }
#pragma unroll
  for (int j = 0; j < 4; ++j) {
    atomicAdd(&s1[tid + j * 256], a[j]);
    atomicAdd(&s2[tid + j * 256], bb[j]);
  }
}

// ---------------------------------------------------------------------------
// K5: batchnorm affine + 64x64 transpose -> out[b][d][s] (f32)
// ---------------------------------------------------------------------------
__global__ __launch_bounds__(256) void norm_k(
    const float* __restrict__ y, const float* __restrict__ s1,
    const float* __restrict__ s2, const float* __restrict__ gamma,
    const float* __restrict__ beta, float* __restrict__ out)
{
  __shared__ float tile[64][65];
  __shared__ float scl[64], sft[64];
  const int tid = threadIdx.x;
  const int s0 = blockIdx.x * 64, d0 = blockIdx.y * 64, b = blockIdx.z;

  if (tid < 64) {
    int d = d0 + tid;
    float mean = s1[d] * (1.f / (float)NBS_);
    float var = s2[d] * (1.f / (float)NBS_) - mean * mean;
    float rstd = rsqrtf(var + EPS_);
    float g = gamma[d];
    scl[tid] = rstd * g;
    sft[tid] = beta[d] - mean * rstd * g;
  }
  __syncthreads();

  const int si = tid >> 2, dc = (tid & 3) * 16;
  const float* row = y + (size_t)(b * S_ + s0 + si) * D_ + d0 + dc;
#pragma unroll
  for (int j = 0; j < 16; ++j)
    tile[si][dc + j] = row[j] * scl[dc + j] + sft[dc + j];
  __syncthreads();

  const int di = tid >> 2, sg = (tid & 3) * 16;
  float* dst = out + (size_t)(b * D_ + d0 + di) * S_ + s0 + sg;
#pragma unroll
  for (int jj = 0; jj < 4; ++jj) {
    float4 p;
    p.x = tile[sg + jj * 4 + 0][di];
    p.y = tile[sg + jj * 4 + 1][di];
    p.z = tile[sg + jj * 4 + 2][di];
    p.w = tile[sg + jj * 4 + 3][di];
    *(float4*)(dst + jj * 4) = p;
  }
}

// ---------------------------------------------------------------------------
extern "C" void kernel_launch(void* const* d_in, const int* in_sizes, int n_in,
                              void* d_out, int out_size, void* d_ws, size_t ws_size,
                              hipStream_t stream)
{
  (void)in_sizes; (void)n_in; (void)out_size; (void)ws_size;
  const float* Q     = (const float*)d_in[0];
  const float* Kin   = (const float*)d_in[1];
  const float* Vin   = (const float*)d_in[2];
  const float* Wq    = (const float*)d_in[3];
  const float* bq    = (const float*)d_in[4];
  const float* Wk    = (const float*)d_in[5];
  const float* bk    = (const float*)d_in[6];
  const float* Wv    = (const float*)d_in[7];
  const float* bv    = (const float*)d_in[8];
  const float* Wo    = (const float*)d_in[9];
  const float* bo    = (const float*)d_in[10];
  const float* gamma = (const float*)d_in[11];
  const float* beta  = (const float*)d_in[12];
  float* out = (float*)d_out;

  char* ws = (char*)d_ws;
  const size_t MB = 1u << 20;
  // xb [0,16M) reused per input; ao overlays [0,16M) after projections
  // wt_q/k/v/o at 16/18/20/22M (2MB each)
  // qb/kb/vb at 24/40/56M (16MB each, peak 72M)
  // y f32 [24,56M) overlays dead qb/kb; stats at 56M overlays dead vb
  ushort_t* xb  = (ushort_t*)(ws);
  ushort_t* wtq = (ushort_t*)(ws + 16 * MB);
  ushort_t* wtk = (ushort_t*)(ws + 18 * MB);
  ushort_t* wtv = (ushort_t*)(ws + 20 * MB);
  ushort_t* wto = (ushort_t*)(ws + 22 * MB);
  ushort_t* qb  = (ushort_t*)(ws + 24 * MB);
  ushort_t* kb  = (ushort_t*)(ws + 40 * MB);
  ushort_t* vb  = (ushort_t*)(ws + 56 * MB);
  ushort_t* ao  = (ushort_t*)(ws);
  float*    y   = (float*)(ws + 24 * MB);
  float*    s1  = (float*)(ws + 56 * MB);
  float*    s2  = (float*)(ws + 56 * MB + 4096);

  wtr_k<<<dim3(16, 16), 256, 0, stream>>>(Wq, wtq, 0);
  wtr_k<<<dim3(16, 16), 256, 0, stream>>>(Wk, wtk, 0);
  wtr_k<<<dim3(16, 16), 256, 0, stream>>>(Wv, wtv, 0);
  wtr_k<<<dim3(16, 16), 256, 0, stream>>>(Wo, wto, 1);

  cvtx_k<<<4096, 256, 0, stream>>>(Q, xb);
  gemm_proj<<<dim3(64, 8), 256, 0, stream>>>(xb, wtq, bq, qb);
  cvtx_k<<<4096, 256, 0, stream>>>(Kin, xb);
  gemm_proj<<<dim3(64, 8), 256, 0, stream>>>(xb, wtk, bk, kb);
  cvtx_k<<<4096, 256, 0, stream>>>(Vin, xb);
  gemm_proj<<<dim3(64, 8), 256, 0, stream>>>(xb, wtv, bv, vb);

  attn_k<<<dim3(32, 16, 4), 256, 0, stream>>>(qb, kb, vb, ao);
  gemm_oproj<<<dim3(64, 8), 256, 0, stream>>>(ao, wto, bo, Q, y);

  hipMemsetAsync(ws + 56 * MB, 0, 8192, stream);
  stats_k<<<256, 256, 0, stream>>>(y, s1, s2);
  norm_k<<<dim3(32, 16, 4), 256, 0, stream>>>(y, s1, s2, gamma, beta, out);
}

// Round 4
// 569.578 us; speedup vs baseline: 2.7109x; 1.0218x over previous
//
#include <hip/hip_runtime.h>

#define B_ 4
#define S_ 2048
#define D_ 1024
#define H_ 16
#define SCALE_ 0.03125f
#define EPS_ 1e-5f
#define NBS_ 8192   // B*S

typedef unsigned short ushort_t;
typedef __attribute__((ext_vector_type(8))) short short8;
typedef __attribute__((ext_vector_type(4))) short short4v;
typedef __attribute__((ext_vector_type(4))) float floatx4;

__device__ __forceinline__ ushort_t f2bf(float f) {
  union { float f; unsigned u; } v; v.f = f;
  unsigned r = v.u + 0x7fffu + ((v.u >> 16) & 1u);
  return (ushort_t)(r >> 16);
}

__device__ __forceinline__ short8 cvt8(float4 a, float4 b) {
  short8 r;
  r[0] = (short)f2bf(a.x); r[1] = (short)f2bf(a.y);
  r[2] = (short)f2bf(a.z); r[3] = (short)f2bf(a.w);
  r[4] = (short)f2bf(b.x); r[5] = (short)f2bf(b.y);
  r[6] = (short)f2bf(b.z); r[7] = (short)f2bf(b.w);
  return r;
}

// async global->LDS, 16B per lane; lds dest = wave-uniform base + lane*16
__device__ __forceinline__ void gload16(const void* g, void* l) {
  __builtin_amdgcn_global_load_lds(
      (const __attribute__((address_space(1))) unsigned int*)g,
      (__attribute__((address_space(3))) unsigned int*)l, 16, 0, 0);
}

// ---------------------------------------------------------------------------
// cvtx_k: f32 -> bf16 elementwise (8 elems/thread)
// ---------------------------------------------------------------------------
__global__ __launch_bounds__(256) void cvtx_k(const float* __restrict__ src,
                                              ushort_t* __restrict__ dst)
{
  size_t i = ((size_t)blockIdx.x * 256 + threadIdx.x) * 8;
  float4 a = *(const float4*)(src + i);
  float4 b = *(const float4*)(src + i + 4);
  *(short8*)(dst + i) = cvt8(a, b);
}

// ---------------------------------------------------------------------------
// wtr_k: weight transpose f32 -> bf16 N x K (k-contiguous).
// mode 0: src = W[h][d][n] ([H,1024,64]); dst[c=h*64+n][d]
// mode 1: src = Wo[c][d] ([1024,1024]);  dst[d][c]
// ---------------------------------------------------------------------------
__global__ __launch_bounds__(256) void wtr_k(const float* __restrict__ src,
                                             ushort_t* __restrict__ dst, int mode)
{
  __shared__ float t[64][65];
  const int tr = blockIdx.x, tc = blockIdx.y;
  const float* sb; int sld;
  if (mode == 0) { sb = src + (size_t)tr * 65536 + (size_t)tc * 64 * 64; sld = 64; }
  else           { sb = src + (size_t)tc * 64 * 1024 + (size_t)tr * 64;  sld = 1024; }
  const int tid = threadIdx.x;
  const int rr = tid >> 2, cs = (tid & 3) * 16;
  const float* p = sb + (size_t)rr * sld + cs;
#pragma unroll
  for (int j = 0; j < 16; ++j) t[rr][cs + j] = p[j];
  __syncthreads();
  ushort_t* dp = dst + (size_t)(tr * 64 + rr) * 1024 + tc * 64 + cs;
#pragma unroll
  for (int j = 0; j < 16; ++j) dp[j] = f2bf(t[cs + j][rr]);
}

// ---------------------------------------------------------------------------
// gemm_proj: C[m][c] = A[m][:] . Bw[c][:] -> out [B][H][S][64] + bias (Q,K)
// ---------------------------------------------------------------------------
__global__ __launch_bounds__(256) void gemm_proj(
    const ushort_t* __restrict__ A, const ushort_t* __restrict__ Bw,
    const float* __restrict__ bias, ushort_t* __restrict__ outp)
{
  __shared__ ushort_t As[128 * 32];
  __shared__ ushort_t Bs[128 * 32];
  const int tid = threadIdx.x;
  const int wv = tid >> 6, lane = tid & 63, quad = lane >> 4, l16 = lane & 15;
  const int m0 = blockIdx.x * 128, n0 = blockIdx.y * 128;
  const int wm = wv & 1, wn = wv >> 1;
  const int lrow = lane >> 2, lkc = (lane & 3) * 8;

  floatx4 acc[4][4];
#pragma unroll
  for (int i = 0; i < 4; ++i)
#pragma unroll
    for (int j = 0; j < 4; ++j) acc[i][j] = (floatx4){0.f, 0.f, 0.f, 0.f};

  for (int k0 = 0; k0 < 1024; k0 += 32) {
    __syncthreads();
#pragma unroll
    for (int j = 0; j < 2; ++j) {
      const int rb = wv * 32 + j * 16;
      gload16(A + (size_t)(m0 + rb + lrow) * 1024 + k0 + lkc, (char*)As + rb * 64);
      gload16(Bw + (size_t)(n0 + rb + lrow) * 1024 + k0 + lkc, (char*)Bs + rb * 64);
    }
    __syncthreads();
    short8 af[4], bf[4];
#pragma unroll
    for (int i = 0; i < 4; ++i)
      af[i] = *(const short8*)&As[(wm * 64 + i * 16 + l16) * 32 + quad * 8];
#pragma unroll
    for (int i = 0; i < 4; ++i)
      bf[i] = *(const short8*)&Bs[(wn * 64 + i * 16 + l16) * 32 + quad * 8];
#pragma unroll
    for (int mi = 0; mi < 4; ++mi)
#pragma unroll
      for (int ni = 0; ni < 4; ++ni)
        acc[mi][ni] = __builtin_amdgcn_mfma_f32_16x16x32_bf16(
            af[mi], bf[ni], acc[mi][ni], 0, 0, 0);
  }

  const int b = m0 >> 11;
  const int sbase = (m0 & 2047) + wm * 64;
#pragma unroll
  for (int ni = 0; ni < 4; ++ni) {
    const int c = n0 + wn * 64 + ni * 16 + l16;
    const int h = c >> 6, nn = c & 63;
    const float bs = bias[c];
    ushort_t* op = outp + (size_t)(b * 16 + h) * 2048 * 64 + nn;
#pragma unroll
    for (int mi = 0; mi < 4; ++mi)
#pragma unroll
      for (int r = 0; r < 4; ++r) {
        int s = sbase + mi * 16 + quad * 4 + r;
        op[(size_t)s * 64] = f2bf(acc[mi][ni][r] + bs);
      }
  }
}

// ---------------------------------------------------------------------------
// gemm_projT: same GEMM but epilogue writes V^T: out[(b*16+h)][dv][s]
// (vectorized short4 stores along s)
// ---------------------------------------------------------------------------
__global__ __launch_bounds__(256) void gemm_projT(
    const ushort_t* __restrict__ A, const ushort_t* __restrict__ Bw,
    const float* __restrict__ bias, ushort_t* __restrict__ outp)
{
  __shared__ ushort_t As[128 * 32];
  __shared__ ushort_t Bs[128 * 32];
  const int tid = threadIdx.x;
  const int wv = tid >> 6, lane = tid & 63, quad = lane >> 4, l16 = lane & 15;
  const int m0 = blockIdx.x * 128, n0 = blockIdx.y * 128;
  const int wm = wv & 1, wn = wv >> 1;
  const int lrow = lane >> 2, lkc = (lane & 3) * 8;

  floatx4 acc[4][4];
#pragma unroll
  for (int i = 0; i < 4; ++i)
#pragma unroll
    for (int j = 0; j < 4; ++j) acc[i][j] = (floatx4){0.f, 0.f, 0.f, 0.f};

  for (int k0 = 0; k0 < 1024; k0 += 32) {
    __syncthreads();
#pragma unroll
    for (int j = 0; j < 2; ++j) {
      const int rb = wv * 32 + j * 16;
      gload16(A + (size_t)(m0 + rb + lrow) * 1024 + k0 + lkc, (char*)As + rb * 64);
      gload16(Bw + (size_t)(n0 + rb + lrow) * 1024 + k0 + lkc, (char*)Bs + rb * 64);
    }
    __syncthreads();
    short8 af[4], bf[4];
#pragma unroll
    for (int i = 0; i < 4; ++i)
      af[i] = *(const short8*)&As[(wm * 64 + i * 16 + l16) * 32 + quad * 8];
#pragma unroll
    for (int i = 0; i < 4; ++i)
      bf[i] = *(const short8*)&Bs[(wn * 64 + i * 16 + l16) * 32 + quad * 8];
#pragma unroll
    for (int mi = 0; mi < 4; ++mi)
#pragma unroll
      for (int ni = 0; ni < 4; ++ni)
        acc[mi][ni] = __builtin_amdgcn_mfma_f32_16x16x32_bf16(
            af[mi], bf[ni], acc[mi][ni], 0, 0, 0);
  }

  const int b = m0 >> 11;
  const int sbase = (m0 & 2047) + wm * 64;
#pragma unroll
  for (int ni = 0; ni < 4; ++ni) {
    const int c = n0 + wn * 64 + ni * 16 + l16;
    const int h = c >> 6, nn = c & 63;
    const float bs = bias[c];
    ushort_t* op = outp + ((size_t)(b * 16 + h) * 64 + nn) * 2048;
#pragma unroll
    for (int mi = 0; mi < 4; ++mi) {
      int s0v = sbase + mi * 16 + quad * 4;
      short4v p;
#pragma unroll
      for (int r = 0; r < 4; ++r) p[r] = (short)f2bf(acc[mi][ni][r] + bs);
      *(short4v*)(op + s0v) = p;
    }
  }
}

// ---------------------------------------------------------------------------
// gemm_oproj: y[m][d] = ao[m][:].Wt_o[d][:] + bo[d] + resid[m][d]  (f32 out)
// ---------------------------------------------------------------------------
__global__ __launch_bounds__(256) void gemm_oproj(
    const ushort_t* __restrict__ A, const ushort_t* __restrict__ Bw,
    const float* __restrict__ bo, const float* __restrict__ resid,
    float* __restrict__ y)
{
  __shared__ ushort_t As[128 * 32];
  __shared__ ushort_t Bs[128 * 32];
  const int tid = threadIdx.x;
  const int wv = tid >> 6, lane = tid & 63, quad = lane >> 4, l16 = lane & 15;
  const int m0 = blockIdx.x * 128, n0 = blockIdx.y * 128;
  const int wm = wv & 1, wn = wv >> 1;
  const int lrow = lane >> 2, lkc = (lane & 3) * 8;

  floatx4 acc[4][4];
#pragma unroll
  for (int i = 0; i < 4; ++i)
#pragma unroll
    for (int j = 0; j < 4; ++j) acc[i][j] = (floatx4){0.f, 0.f, 0.f, 0.f};

  for (int k0 = 0; k0 < 1024; k0 += 32) {
    __syncthreads();
#pragma unroll
    for (int j = 0; j < 2; ++j) {
      const int rb = wv * 32 + j * 16;
      gload16(A + (size_t)(m0 + rb + lrow) * 1024 + k0 + lkc, (char*)As + rb * 64);
      gload16(Bw + (size_t)(n0 + rb + lrow) * 1024 + k0 + lkc, (char*)Bs + rb * 64);
    }
    __syncthreads();
    short8 af[4], bf[4];
#pragma unroll
    for (int i = 0; i < 4; ++i)
      af[i] = *(const short8*)&As[(wm * 64 + i * 16 + l16) * 32 + quad * 8];
#pragma unroll
    for (int i = 0; i < 4; ++i)
      bf[i] = *(const short8*)&Bs[(wn * 64 + i * 16 + l16) * 32 + quad * 8];
#pragma unroll
    for (int mi = 0; mi < 4; ++mi)
#pragma unroll
      for (int ni = 0; ni < 4; ++ni)
        acc[mi][ni] = __builtin_amdgcn_mfma_f32_16x16x32_bf16(
            af[mi], bf[ni], acc[mi][ni], 0, 0, 0);
  }

  const int mb = m0 + wm * 64;
#pragma unroll
  for (int ni = 0; ni < 4; ++ni) {
    const int d = n0 + wn * 64 + ni * 16 + l16;
    const float bs = bo[d];
#pragma unroll
    for (int mi = 0; mi < 4; ++mi)
#pragma unroll
      for (int r = 0; r < 4; ++r) {
        int m = mb + mi * 16 + quad * 4 + r;
        y[(size_t)m * 1024 + d] = acc[mi][ni][r] + bs + resid[(size_t)m * 1024 + d];
      }
  }
}

// ---------------------------------------------------------------------------
// attn_k v2: flash attention. Block 256 = 4 waves; 128 Q rows/block (wave owns
// 32 rows = 2 blocks of 16). K/V^T tiles of 64 staged frag-major via
// global_load_lds -> conflict-free lane-linear ds_read_b128.
// q,k: bf16 [B,H,S,64]; vt: bf16 [B*H][64][S] (V^T); ao: bf16 [B,S,H*64]
// ---------------------------------------------------------------------------
__global__ __launch_bounds__(256) void attn_k(
    const ushort_t* __restrict__ q, const ushort_t* __restrict__ k,
    const ushort_t* __restrict__ vt, ushort_t* __restrict__ ao)
{
  __shared__ ushort_t lds[16384];   // Ks 4096 | Vs 4096 | Ps 8192 (ushorts)
  ushort_t* Ks = lds;
  ushort_t* Vs = lds + 4096;
  ushort_t* Ps = lds + 8192;

  const int tid = threadIdx.x;
  const int wv = tid >> 6, lane = tid & 63, quad = lane >> 4, l16 = lane & 15;
  const int q0 = blockIdx.x * 128, h = blockIdx.y, b = blockIdx.z;
  const size_t bh = (size_t)(b * H_ + h) * S_;
  const ushort_t* vb = vt + (size_t)(b * H_ + h) * 64 * S_;

  // Q fragments (held all kernel): aq[rb][half]
  short8 aq[2][2];
#pragma unroll
  for (int rb = 0; rb < 2; ++rb) {
    const ushort_t* qrow = q + (bh + q0 + wv * 32 + rb * 16 + l16) * 64;
    aq[rb][0] = *(const short8*)(qrow + quad * 8);
    aq[rb][1] = *(const short8*)(qrow + 32 + quad * 8);
  }

  floatx4 o[2][4];
  float m[2][4], l[2][4];
#pragma unroll
  for (int rb = 0; rb < 2; ++rb) {
#pragma unroll
    for (int cb = 0; cb < 4; ++cb) o[rb][cb] = (floatx4){0.f, 0.f, 0.f, 0.f};
#pragma unroll
    for (int r = 0; r < 4; ++r) { m[rb][r] = -1e30f; l[rb][r] = 0.f; }
  }

  // P frag-major write base (per-lane invariant part)
  const int pbase = wv * 2048 + (l16 >> 3) * 128 + quad * 32 + (l16 & 7);

  for (int t0 = 0; t0 < S_; t0 += 64) {
    __syncthreads();
    // stage: 16 blocks of 1KB (K: 8, V^T: 8); wave wv does blocks wv*4..+3
#pragma unroll
    for (int i = 0; i < 4; ++i) {
      const int idx = wv * 4 + i;
      const int cb = (idx >> 1) & 3, hf = idx & 1;
      if (idx < 8)
        gload16(k + (bh + t0 + cb * 16 + l16) * 64 + hf * 32 + quad * 8,
                (char*)Ks + idx * 1024);
      else
        gload16(vb + (size_t)(cb * 16 + l16) * S_ + t0 + hf * 32 + quad * 8,
                (char*)Vs + (idx - 8) * 1024);
    }
    __syncthreads();

    // QK^T: sc[rb][cb], C-layout row=quad*4+r, col(t)=cb*16+l16
    floatx4 sc[2][4];
#pragma unroll
    for (int rb = 0; rb < 2; ++rb)
#pragma unroll
      for (int cb = 0; cb < 4; ++cb) sc[rb][cb] = (floatx4){0.f, 0.f, 0.f, 0.f};
#pragma unroll
    for (int hf = 0; hf < 2; ++hf) {
      short8 bk[4];
#pragma unroll
      for (int cb = 0; cb < 4; ++cb)
        bk[cb] = *(const short8*)&Ks[(cb * 2 + hf) * 512 + lane * 8];
#pragma unroll
      for (int rb = 0; rb < 2; ++rb)
#pragma unroll
        for (int cb = 0; cb < 4; ++cb)
          sc[rb][cb] = __builtin_amdgcn_mfma_f32_16x16x32_bf16(
              aq[rb][hf], bk[cb], sc[rb][cb], 0, 0, 0);
    }

    // online softmax + P write (frag-major, per-wave region)
#pragma unroll
    for (int rb = 0; rb < 2; ++rb) {
      float mx[4];
#pragma unroll
      for (int r = 0; r < 4; ++r) mx[r] = -1e30f;
#pragma unroll
      for (int cb = 0; cb < 4; ++cb)
#pragma unroll
        for (int r = 0; r < 4; ++r) {
          sc[rb][cb][r] *= SCALE_;
          mx[r] = fmaxf(mx[r], sc[rb][cb][r]);
        }
#pragma unroll
      for (int off = 8; off >= 1; off >>= 1)
#pragma unroll
        for (int r = 0; r < 4; ++r) mx[r] = fmaxf(mx[r], __shfl_xor(mx[r], off));

      float alpha[4], rs[4];
#pragma unroll
      for (int r = 0; r < 4; ++r) {
        float mn = fmaxf(m[rb][r], mx[r]);
        alpha[r] = __expf(m[rb][r] - mn);
        m[rb][r] = mn;
        rs[r] = 0.f;
      }
#pragma unroll
      for (int cb = 0; cb < 4; ++cb)
#pragma unroll
        for (int r = 0; r < 4; ++r) {
          float p = __expf(sc[rb][cb][r] - m[rb][r]);
          sc[rb][cb][r] = p;
          rs[r] += p;
        }
#pragma unroll
      for (int off = 8; off >= 1; off >>= 1)
#pragma unroll
        for (int r = 0; r < 4; ++r) rs[r] += __shfl_xor(rs[r], off);
#pragma unroll
      for (int r = 0; r < 4; ++r) l[rb][r] = l[rb][r] * alpha[r] + rs[r];
#pragma unroll
      for (int cb = 0; cb < 4; ++cb)
#pragma unroll
        for (int r = 0; r < 4; ++r) o[rb][cb][r] *= alpha[r];

#pragma unroll
      for (int cb = 0; cb < 4; ++cb)
#pragma unroll
        for (int r = 0; r < 4; ++r)
          Ps[pbase + rb * 1024 + (cb >> 1) * 512 + (cb & 1) * 256 + r * 8] =
              f2bf(sc[rb][cb][r]);
    }
    // wave-local LDS visibility: drain LDS queue, block scheduler motion
    asm volatile("s_waitcnt lgkmcnt(0)" ::: "memory");
    __builtin_amdgcn_wave_barrier();

    // PV: o += P . V  (A=P frag-major, B=V^T frag-major)
#pragma unroll
    for (int hf = 0; hf < 2; ++hf) {
      short8 bvf[4];
#pragma unroll
      for (int cb = 0; cb < 4; ++cb)
        bvf[cb] = *(const short8*)&Vs[(cb * 2 + hf) * 512 + lane * 8];
#pragma unroll
      for (int rb = 0; rb < 2; ++rb) {
        short8 ap = *(const short8*)&Ps[wv * 2048 + rb * 1024 + hf * 512 + lane * 8];
#pragma unroll
        for (int cb = 0; cb < 4; ++cb)
          o[rb][cb] = __builtin_amdgcn_mfma_f32_16x16x32_bf16(
              ap, bvf[cb], o[rb][cb], 0, 0, 0);
      }
    }
  }

  // epilogue: divide by l, write concat-head layout [B][S][H*64]
#pragma unroll
  for (int rb = 0; rb < 2; ++rb)
#pragma unroll
    for (int cb = 0; cb < 4; ++cb)
#pragma unroll
      for (int r = 0; r < 4; ++r) {
        float val = o[rb][cb][r] / l[rb][r];
        size_t idx = (size_t)(b * S_ + q0 + wv * 32 + rb * 16 + quad * 4 + r) * 1024
                     + h * 64 + cb * 16 + l16;
        ao[idx] = f2bf(val);
      }
}

// ---------------------------------------------------------------------------
// K4: per-channel sum / sumsq over 8192 samples.
// ---------------------------------------------------------------------------
__global__ __launch_bounds__(256) void stats_k(
    const float* __restrict__ y, float* __restrict__ s1, float* __restrict__ s2)
{
  const int tid = threadIdx.x;
  const int r0 = blockIdx.x * 32;
  float a[4] = {0.f, 0.f, 0.f, 0.f}, bb[4] = {0.f, 0.f, 0.f, 0.f};
  for (int r = 0; r < 32; ++r) {
    const float* row = y + (size_t)(r0 + r) * D_;
#pragma unroll
    for (int j = 0; j < 4; ++j) {
      float vv = row[tid + j * 256];
      a[j] += vv;
      bb[j] += vv * vv;
    }
  }
#pragma unroll
  for (int j = 0; j < 4; ++j) {
    atomicAdd(&s1[tid + j * 256], a[j]);
    atomicAdd(&s2[tid + j * 256], bb[j]);
  }
}

// ---------------------------------------------------------------------------
// K5: batchnorm affine + 64x64 transpose -> out[b][d][s] (f32)
// ---------------------------------------------------------------------------
__global__ __launch_bounds__(256) void norm_k(
    const float* __restrict__ y, const float* __restrict__ s1,
    const float* __restrict__ s2, const float* __restrict__ gamma,
    const float* __restrict__ beta, float* __restrict__ out)
{
  __shared__ float tile[64][65];
  __shared__ float scl[64], sft[64];
  const int tid = threadIdx.x;
  const int s0 = blockIdx.x * 64, d0 = blockIdx.y * 64, b = blockIdx.z;

  if (tid < 64) {
    int d = d0 + tid;
    float mean = s1[d] * (1.f / (float)NBS_);
    float var = s2[d] * (1.f / (float)NBS_) - mean * mean;
    float rstd = rsqrtf(var + EPS_);
    float g = gamma[d];
    scl[tid] = rstd * g;
    sft[tid] = beta[d] - mean * rstd * g;
  }
  __syncthreads();

  const int si = tid >> 2, dc = (tid & 3) * 16;
  const float* row = y + (size_t)(b * S_ + s0 + si) * D_ + d0 + dc;
#pragma unroll
  for (int j = 0; j < 16; ++j)
    tile[si][dc + j] = row[j] * scl[dc + j] + sft[dc + j];
  __syncthreads();

  const int di = tid >> 2, sg = (tid & 3) * 16;
  float* dst = out + (size_t)(b * D_ + d0 + di) * S_ + s0 + sg;
#pragma unroll
  for (int jj = 0; jj < 4; ++jj) {
    float4 p;
    p.x = tile[sg + jj * 4 + 0][di];
    p.y = tile[sg + jj * 4 + 1][di];
    p.z = tile[sg + jj * 4 + 2][di];
    p.w = tile[sg + jj * 4 + 3][di];
    *(float4*)(dst + jj * 4) = p;
  }
}

// ---------------------------------------------------------------------------
extern "C" void kernel_launch(void* const* d_in, const int* in_sizes, int n_in,
                              void* d_out, int out_size, void* d_ws, size_t ws_size,
                              hipStream_t stream)
{
  (void)in_sizes; (void)n_in; (void)out_size; (void)ws_size;
  const float* Q     = (const float*)d_in[0];
  const float* Kin   = (const float*)d_in[1];
  const float* Vin   = (const float*)d_in[2];
  const float* Wq    = (const float*)d_in[3];
  const float* bq    = (const float*)d_in[4];
  const float* Wk    = (const float*)d_in[5];
  const float* bk    = (const float*)d_in[6];
  const float* Wv    = (const float*)d_in[7];
  const float* bv    = (const float*)d_in[8];
  const float* Wo    = (const float*)d_in[9];
  const float* bo    = (const float*)d_in[10];
  const float* gamma = (const float*)d_in[11];
  const float* beta  = (const float*)d_in[12];
  float* out = (float*)d_out;

  char* ws = (char*)d_ws;
  const size_t MB = 1u << 20;
  // xb [0,16M) reused per input; ao overlays [0,16M) after projections
  // wt_q/k/v/o at 16/18/20/22M; qb/kb at 24/40M; vtb (V^T) at 56M
  // y f32 [24,56M) overlays dead qb/kb; stats at 56M overlays dead vtb
  ushort_t* xb  = (ushort_t*)(ws);
  ushort_t* wtq = (ushort_t*)(ws + 16 * MB);
  ushort_t* wtk = (ushort_t*)(ws + 18 * MB);
  ushort_t* wtv = (ushort_t*)(ws + 20 * MB);
  ushort_t* wto = (ushort_t*)(ws + 22 * MB);
  ushort_t* qb  = (ushort_t*)(ws + 24 * MB);
  ushort_t* kb  = (ushort_t*)(ws + 40 * MB);
  ushort_t* vtb = (ushort_t*)(ws + 56 * MB);
  ushort_t* ao  = (ushort_t*)(ws);
  float*    y   = (float*)(ws + 24 * MB);
  float*    s1  = (float*)(ws + 56 * MB);
  float*    s2  = (float*)(ws + 56 * MB + 4096);

  wtr_k<<<dim3(16, 16), 256, 0, stream>>>(Wq, wtq, 0);
  wtr_k<<<dim3(16, 16), 256, 0, stream>>>(Wk, wtk, 0);
  wtr_k<<<dim3(16, 16), 256, 0, stream>>>(Wv, wtv, 0);
  wtr_k<<<dim3(16, 16), 256, 0, stream>>>(Wo, wto, 1);

  cvtx_k<<<4096, 256, 0, stream>>>(Q, xb);
  gemm_proj<<<dim3(64, 8), 256, 0, stream>>>(xb, wtq, bq, qb);
  cvtx_k<<<4096, 256, 0, stream>>>(Kin, xb);
  gemm_proj<<<dim3(64, 8), 256, 0, stream>>>(xb, wtk, bk, kb);
  cvtx_k<<<4096, 256, 0, stream>>>(Vin, xb);
  gemm_projT<<<dim3(64, 8), 256, 0, stream>>>(xb, wtv, bv, vtb);

  attn_k<<<dim3(16, 16, 4), 256, 0, stream>>>(qb, kb, vtb, ao);
  gemm_oproj<<<dim3(64, 8), 256, 0, stream>>>(ao, wto, bo, Q, y);

  hipMemsetAsync(ws + 56 * MB, 0, 8192, stream);
  stats_k<<<256, 256, 0, stream>>>(y, s1, s2);
  norm_k<<<dim3(32, 16, 4), 256, 0, stream>>>(y, s1, s2, gamma, beta, out);
}

// Round 6
// 458.842 us; speedup vs baseline: 3.3652x; 1.2413x over previous
//
#include <hip/hip_runtime.h>

#define B_ 4
#define S_ 2048
#define D_ 1024
#define H_ 16
#define SCALE_ 0.03125f
#define EPS_ 1e-5f
#define NBS_ 8192   // B*S

typedef unsigned short ushort_t;
typedef __attribute__((ext_vector_type(8))) short short8;
typedef __attribute__((ext_vector_type(4))) short short4v;
typedef __attribute__((ext_vector_type(4))) float floatx4;

__device__ __forceinline__ ushort_t f2bf(float f) {
  union { float f; unsigned u; } v; v.f = f;
  unsigned r = v.u + 0x7fffu + ((v.u >> 16) & 1u);
  return (ushort_t)(r >> 16);
}

__device__ __forceinline__ float fast_exp2(float x) {
#if __has_builtin(__builtin_amdgcn_exp2f)
  return __builtin_amdgcn_exp2f(x);
#else
  return __expf(x * 0.6931471805599453f);
#endif
}

__device__ __forceinline__ short8 cvt8(float4 a, float4 b) {
  short8 r;
  r[0] = (short)f2bf(a.x); r[1] = (short)f2bf(a.y);
  r[2] = (short)f2bf(a.z); r[3] = (short)f2bf(a.w);
  r[4] = (short)f2bf(b.x); r[5] = (short)f2bf(b.y);
  r[6] = (short)f2bf(b.z); r[7] = (short)f2bf(b.w);
  return r;
}

// async global->LDS, 16B per lane; lds dest = wave-uniform base + lane*16
__device__ __forceinline__ void gload16(const void* g, void* l) {
  __builtin_amdgcn_global_load_lds(
      (const __attribute__((address_space(1))) unsigned int*)g,
      (__attribute__((address_space(3))) unsigned int*)l, 16, 0, 0);
}

// ---------------------------------------------------------------------------
// cvtx_k: f32 -> bf16 elementwise (8 elems/thread)
// ---------------------------------------------------------------------------
__global__ __launch_bounds__(256) void cvtx_k(const float* __restrict__ src,
                                              ushort_t* __restrict__ dst)
{
  size_t i = ((size_t)blockIdx.x * 256 + threadIdx.x) * 8;
  float4 a = *(const float4*)(src + i);
  float4 b = *(const float4*)(src + i + 4);
  *(short8*)(dst + i) = cvt8(a, b);
}

// ---------------------------------------------------------------------------
// wtr_k: weight transpose f32 -> bf16 N x K (k-contiguous).
// mode 0: src = W[h][d][n] ([H,1024,64]); dst[c=h*64+n][d]
// mode 1: src = Wo[c][d] ([1024,1024]);  dst[d][c]
// ---------------------------------------------------------------------------
__global__ __launch_bounds__(256) void wtr_k(const float* __restrict__ src,
                                             ushort_t* __restrict__ dst, int mode)
{
  __shared__ float t[64][65];
  const int tr = blockIdx.x, tc = blockIdx.y;
  const float* sb; int sld;
  if (mode == 0) { sb = src + (size_t)tr * 65536 + (size_t)tc * 64 * 64; sld = 64; }
  else           { sb = src + (size_t)tc * 64 * 1024 + (size_t)tr * 64;  sld = 1024; }
  const int tid = threadIdx.x;
  const int rr = tid >> 2, cs = (tid & 3) * 16;
  const float* p = sb + (size_t)rr * sld + cs;
#pragma unroll
  for (int j = 0; j < 16; ++j) t[rr][cs + j] = p[j];
  __syncthreads();
  ushort_t* dp = dst + (size_t)(tr * 64 + rr) * 1024 + tc * 64 + cs;
#pragma unroll
  for (int j = 0; j < 16; ++j) dp[j] = f2bf(t[cs + j][rr]);
}

// ---------------------------------------------------------------------------
// gemm_proj: C[m][c] = (A[m][:].Bw[c][:] + bias[c]) * scale -> [B][H][S][64]
// ---------------------------------------------------------------------------
__global__ __launch_bounds__(256) void gemm_proj(
    const ushort_t* __restrict__ A, const ushort_t* __restrict__ Bw,
    const float* __restrict__ bias, ushort_t* __restrict__ outp, float scale)
{
  __shared__ ushort_t As[128 * 32];
  __shared__ ushort_t Bs[128 * 32];
  const int tid = threadIdx.x;
  const int wv = tid >> 6, lane = tid & 63, quad = lane >> 4, l16 = lane & 15;
  const int m0 = blockIdx.x * 128, n0 = blockIdx.y * 128;
  const int wm = wv & 1, wn = wv >> 1;
  const int lrow = lane >> 2, lkc = (lane & 3) * 8;

  floatx4 acc[4][4];
#pragma unroll
  for (int i = 0; i < 4; ++i)
#pragma unroll
    for (int j = 0; j < 4; ++j) acc[i][j] = (floatx4){0.f, 0.f, 0.f, 0.f};

  for (int k0 = 0; k0 < 1024; k0 += 32) {
    __syncthreads();
#pragma unroll
    for (int j = 0; j < 2; ++j) {
      const int rb = wv * 32 + j * 16;
      gload16(A + (size_t)(m0 + rb + lrow) * 1024 + k0 + lkc, (char*)As + rb * 64);
      gload16(Bw + (size_t)(n0 + rb + lrow) * 1024 + k0 + lkc, (char*)Bs + rb * 64);
    }
    __syncthreads();
    short8 af[4], bf[4];
#pragma unroll
    for (int i = 0; i < 4; ++i)
      af[i] = *(const short8*)&As[(wm * 64 + i * 16 + l16) * 32 + quad * 8];
#pragma unroll
    for (int i = 0; i < 4; ++i)
      bf[i] = *(const short8*)&Bs[(wn * 64 + i * 16 + l16) * 32 + quad * 8];
#pragma unroll
    for (int mi = 0; mi < 4; ++mi)
#pragma unroll
      for (int ni = 0; ni < 4; ++ni)
        acc[mi][ni] = __builtin_amdgcn_mfma_f32_16x16x32_bf16(
            af[mi], bf[ni], acc[mi][ni], 0, 0, 0);
  }

  const int b = m0 >> 11;
  const int sbase = (m0 & 2047) + wm * 64;
#pragma unroll
  for (int ni = 0; ni < 4; ++ni) {
    const int c = n0 + wn * 64 + ni * 16 + l16;
    const int h = c >> 6, nn = c & 63;
    const float bs = bias[c];
    ushort_t* op = outp + (size_t)(b * 16 + h) * 2048 * 64 + nn;
#pragma unroll
    for (int mi = 0; mi < 4; ++mi)
#pragma unroll
      for (int r = 0; r < 4; ++r) {
        int s = sbase + mi * 16 + quad * 4 + r;
        op[(size_t)s * 64] = f2bf((acc[mi][ni][r] + bs) * scale);
      }
  }
}

// ---------------------------------------------------------------------------
// gemm_projT: same GEMM but epilogue writes V^T: out[(b*16+h)][dv][s]
// ---------------------------------------------------------------------------
__global__ __launch_bounds__(256) void gemm_projT(
    const ushort_t* __restrict__ A, const ushort_t* __restrict__ Bw,
    const float* __restrict__ bias, ushort_t* __restrict__ outp)
{
  __shared__ ushort_t As[128 * 32];
  __shared__ ushort_t Bs[128 * 32];
  const int tid = threadIdx.x;
  const int wv = tid >> 6, lane = tid & 63, quad = lane >> 4, l16 = lane & 15;
  const int m0 = blockIdx.x * 128, n0 = blockIdx.y * 128;
  const int wm = wv & 1, wn = wv >> 1;
  const int lrow = lane >> 2, lkc = (lane & 3) * 8;

  floatx4 acc[4][4];
#pragma unroll
  for (int i = 0; i < 4; ++i)
#pragma unroll
    for (int j = 0; j < 4; ++j) acc[i][j] = (floatx4){0.f, 0.f, 0.f, 0.f};

  for (int k0 = 0; k0 < 1024; k0 += 32) {
    __syncthreads();
#pragma unroll
    for (int j = 0; j < 2; ++j) {
      const int rb = wv * 32 + j * 16;
      gload16(A + (size_t)(m0 + rb + lrow) * 1024 + k0 + lkc, (char*)As + rb * 64);
      gload16(Bw + (size_t)(n0 + rb + lrow) * 1024 + k0 + lkc, (char*)Bs + rb * 64);
    }
    __syncthreads();
    short8 af[4], bf[4];
#pragma unroll
    for (int i = 0; i < 4; ++i)
      af[i] = *(const short8*)&As[(wm * 64 + i * 16 + l16) * 32 + quad * 8];
#pragma unroll
    for (int i = 0; i < 4; ++i)
      bf[i] = *(const short8*)&Bs[(wn * 64 + i * 16 + l16) * 32 + quad * 8];
#pragma unroll
    for (int mi = 0; mi < 4; ++mi)
#pragma unroll
      for (int ni = 0; ni < 4; ++ni)
        acc[mi][ni] = __builtin_amdgcn_mfma_f32_16x16x32_bf16(
            af[mi], bf[ni], acc[mi][ni], 0, 0, 0);
  }

  const int b = m0 >> 11;
  const int sbase = (m0 & 2047) + wm * 64;
#pragma unroll
  for (int ni = 0; ni < 4; ++ni) {
    const int c = n0 + wn * 64 + ni * 16 + l16;
    const int h = c >> 6, nn = c & 63;
    const float bs = bias[c];
    ushort_t* op = outp + ((size_t)(b * 16 + h) * 64 + nn) * 2048;
#pragma unroll
    for (int mi = 0; mi < 4; ++mi) {
      int s0v = sbase + mi * 16 + quad * 4;
      short4v p;
#pragma unroll
      for (int r = 0; r < 4; ++r) p[r] = (short)f2bf(acc[mi][ni][r] + bs);
      *(short4v*)(op + s0v) = p;
    }
  }
}

// ---------------------------------------------------------------------------
// gemm_oproj: y[m][d] = ao[m][:].Wt_o[d][:] + bo[d] + resid[m][d]  (f32 out)
// ---------------------------------------------------------------------------
__global__ __launch_bounds__(256) void gemm_oproj(
    const ushort_t* __restrict__ A, const ushort_t* __restrict__ Bw,
    const float* __restrict__ bo, const float* __restrict__ resid,
    float* __restrict__ y)
{
  __shared__ ushort_t As[128 * 32];
  __shared__ ushort_t Bs[128 * 32];
  const int tid = threadIdx.x;
  const int wv = tid >> 6, lane = tid & 63, quad = lane >> 4, l16 = lane & 15;
  const int m0 = blockIdx.x * 128, n0 = blockIdx.y * 128;
  const int wm = wv & 1, wn = wv >> 1;
  const int lrow = lane >> 2, lkc = (lane & 3) * 8;

  floatx4 acc[4][4];
#pragma unroll
  for (int i = 0; i < 4; ++i)
#pragma unroll
    for (int j = 0; j < 4; ++j) acc[i][j] = (floatx4){0.f, 0.f, 0.f, 0.f};

  for (int k0 = 0; k0 < 1024; k0 += 32) {
    __syncthreads();
#pragma unroll
    for (int j = 0; j < 2; ++j) {
      const int rb = wv * 32 + j * 16;
      gload16(A + (size_t)(m0 + rb + lrow) * 1024 + k0 + lkc, (char*)As + rb * 64);
      gload16(Bw + (size_t)(n0 + rb + lrow) * 1024 + k0 + lkc, (char*)Bs + rb * 64);
    }
    __syncthreads();
    short8 af[4], bf[4];
#pragma unroll
    for (int i = 0; i < 4; ++i)
      af[i] = *(const short8*)&As[(wm * 64 + i * 16 + l16) * 32 + quad * 8];
#pragma unroll
    for (int i = 0; i < 4; ++i)
      bf[i] = *(const short8*)&Bs[(wn * 64 + i * 16 + l16) * 32 + quad * 8];
#pragma unroll
    for (int mi = 0; mi < 4; ++mi)
#pragma unroll
      for (int ni = 0; ni < 4; ++ni)
        acc[mi][ni] = __builtin_amdgcn_mfma_f32_16x16x32_bf16(
            af[mi], bf[ni], acc[mi][ni], 0, 0, 0);
  }

  const int mb = m0 + wm * 64;
#pragma unroll
  for (int ni = 0; ni < 4; ++ni) {
    const int d = n0 + wn * 64 + ni * 16 + l16;
    const float bs = bo[d];
#pragma unroll
    for (int mi = 0; mi < 4; ++mi)
#pragma unroll
      for (int r = 0; r < 4; ++r) {
        int m = mb + mi * 16 + quad * 4 + r;
        y[(size_t)m * 1024 + d] = acc[mi][ni][r] + bs + resid[(size_t)m * 1024 + d];
      }
  }
}

// ---------------------------------------------------------------------------
// attn_k v3b: flash attention, softmax-light (no running max; q pre-scaled by
// SCALE*log2e), double-buffered K/V staging.
// LDS byte map: K dbuf [0,16384) | V dbuf [16384,32768) | P [32768,40960)
// ---------------------------------------------------------------------------
__global__ __launch_bounds__(256, 4) void attn_k(
    const ushort_t* __restrict__ q, const ushort_t* __restrict__ k,
    const ushort_t* __restrict__ vt, ushort_t* __restrict__ ao)
{
  __shared__ ushort_t lds[20480];
  const int tid = threadIdx.x;
  const int wv = tid >> 6, lane = tid & 63, quad = lane >> 4, l16 = lane & 15;
  const int q0 = blockIdx.x * 128, h = blockIdx.y, b = blockIdx.z;
  const size_t bh = (size_t)(b * H_ + h) * S_;
  const ushort_t* vb = vt + (size_t)(b * H_ + h) * 64 * S_;

  // Q fragments (held all kernel): aq[rb][half]; q pre-scaled by SCALE*log2e
  short8 aq[2][2];
#pragma unroll
  for (int rb = 0; rb < 2; ++rb) {
    const ushort_t* qrow = q + (bh + q0 + wv * 32 + rb * 16 + l16) * 64;
    aq[rb][0] = *(const short8*)(qrow + quad * 8);
    aq[rb][1] = *(const short8*)(qrow + 32 + quad * 8);
  }

  floatx4 o[2][4];
  float ll[2][4];
#pragma unroll
  for (int rb = 0; rb < 2; ++rb) {
#pragma unroll
    for (int cb = 0; cb < 4; ++cb) o[rb][cb] = (floatx4){0.f, 0.f, 0.f, 0.f};
#pragma unroll
    for (int r = 0; r < 4; ++r) ll[rb][r] = 0.f;
  }

  // P write base (per-wave region, frag-major; rb processed sequentially)
  const int pbase = 16384 + wv * 1024 + (l16 >> 3) * 128 + quad * 32 + (l16 & 7);

  // stage(nb, t0): K block idx -> bytes nb*8192 + idx*1024 (idx = cb*2+hf)
  //                V block     -> bytes 16384 + nb*8192 + (idx-8)*1024
  auto stage = [&](int nb, int t0) {
#pragma unroll
    for (int i = 0; i < 4; ++i) {
      const int idx = wv * 4 + i;
      const int cb = (idx >> 1) & 3, hf = idx & 1;
      if (idx < 8)
        gload16(k + (bh + t0 + cb * 16 + l16) * 64 + hf * 32 + quad * 8,
                (char*)lds + nb * 8192 + idx * 1024);
      else
        gload16(vb + (size_t)(cb * 16 + l16) * S_ + t0 + hf * 32 + quad * 8,
                (char*)lds + 16384 + nb * 8192 + (idx - 8) * 1024);
    }
  };

  stage(0, 0);
  asm volatile("s_waitcnt vmcnt(0)" ::: "memory");
  __syncthreads();

  for (int t0 = 0; t0 < S_; t0 += 64) {
    const int nb = (t0 >> 6) & 1;
    const ushort_t* KsC = lds + nb * 4096;          // ushort offsets
    const ushort_t* VsC = lds + 8192 + nb * 4096;
    if (t0 + 64 < S_) stage(nb ^ 1, t0 + 64);

    // QK^T in exp2 domain; C-layout row=quad*4+r, col=cb*16+l16
    floatx4 sc[2][4];
#pragma unroll
    for (int rb = 0; rb < 2; ++rb)
#pragma unroll
      for (int cb = 0; cb < 4; ++cb) sc[rb][cb] = (floatx4){0.f, 0.f, 0.f, 0.f};
#pragma unroll
    for (int hf = 0; hf < 2; ++hf) {
      short8 bk[4];
#pragma unroll
      for (int cb = 0; cb < 4; ++cb)
        bk[cb] = *(const short8*)&KsC[(cb * 2 + hf) * 512 + lane * 8];
#pragma unroll
      for (int rb = 0; rb < 2; ++rb)
#pragma unroll
        for (int cb = 0; cb < 4; ++cb)
          sc[rb][cb] = __builtin_amdgcn_mfma_f32_16x16x32_bf16(
              aq[rb][hf], bk[cb], sc[rb][cb], 0, 0, 0);
    }

    // per-rb: p = 2^s, lane-partial l, P round-trip, PV
#pragma unroll
    for (int rb = 0; rb < 2; ++rb) {
#pragma unroll
      for (int cb = 0; cb < 4; ++cb)
#pragma unroll
        for (int r = 0; r < 4; ++r) {
          float p = fast_exp2(sc[rb][cb][r]);
          ll[rb][r] += p;
          lds[pbase + (cb >> 1) * 512 + (cb & 1) * 256 + r * 8] = f2bf(p);
        }
      asm volatile("s_waitcnt lgkmcnt(0)" ::: "memory");
      __builtin_amdgcn_wave_barrier();
#pragma unroll
      for (int hf = 0; hf < 2; ++hf) {
        short8 ap = *(const short8*)&lds[16384 + wv * 1024 + hf * 512 + lane * 8];
        short8 bvf[4];
#pragma unroll
        for (int cb = 0; cb < 4; ++cb)
          bvf[cb] = *(const short8*)&VsC[(cb * 2 + hf) * 512 + lane * 8];
#pragma unroll
        for (int cb = 0; cb < 4; ++cb)
          o[rb][cb] = __builtin_amdgcn_mfma_f32_16x16x32_bf16(
              ap, bvf[cb], o[rb][cb], 0, 0, 0);
      }
      // rb=1 rewrites the same P slots; ds ops within a wave retire in order
      asm volatile("s_waitcnt lgkmcnt(0)" ::: "memory");
      __builtin_amdgcn_wave_barrier();
    }

    asm volatile("s_waitcnt vmcnt(0)" ::: "memory");  // prefetch landed
    __syncthreads();
  }

  // epilogue: reduce l across the 16 col-lanes (quad-local), write [B][S][H*64]
#pragma unroll
  for (int rb = 0; rb < 2; ++rb)
#pragma unroll
    for (int r = 0; r < 4; ++r) {
#pragma unroll
      for (int off = 8; off >= 1; off >>= 1)
        ll[rb][r] += __shfl_xor(ll[rb][r], off);
      ll[rb][r] = 1.f / ll[rb][r];
    }
#pragma unroll
  for (int rb = 0; rb < 2; ++rb)
#pragma unroll
    for (int cb = 0; cb < 4; ++cb)
#pragma unroll
      for (int r = 0; r < 4; ++r) {
        float val = o[rb][cb][r] * ll[rb][r];
        size_t idx = (size_t)(b * S_ + q0 + wv * 32 + rb * 16 + quad * 4 + r) * 1024
                     + h * 64 + cb * 16 + l16;
        ao[idx] = f2bf(val);
      }
}

// ---------------------------------------------------------------------------
// K4: per-channel sum / sumsq over 8192 samples.
// ---------------------------------------------------------------------------
__global__ __launch_bounds__(256) void stats_k(
    const float* __restrict__ y, float* __restrict__ s1, float* __restrict__ s2)
{
  const int tid = threadIdx.x;
  const int r0 = blockIdx.x * 32;
  float a[4] = {0.f, 0.f, 0.f, 0.f}, bb[4] = {0.f, 0.f, 0.f, 0.f};
  for (int r = 0; r < 32; ++r) {
    const float* row = y + (size_t)(r0 + r) * D_;
#pragma unroll
    for (int j = 0; j < 4; ++j) {
      float vv = row[tid + j * 256];
      a[j] += vv;
      bb[j] += vv * vv;
    }
  }
#pragma unroll
  for (int j = 0; j < 4; ++j) {
    atomicAdd(&s1[tid + j * 256], a[j]);
    atomicAdd(&s2[tid + j * 256], bb[j]);
  }
}

// ---------------------------------------------------------------------------
// K5: batchnorm affine + 64x64 transpose -> out[b][d][s] (f32)
// ---------------------------------------------------------------------------
__global__ __launch_bounds__(256) void norm_k(
    const float* __restrict__ y, const float* __restrict__ s1,
    const float* __restrict__ s2, const float* __restrict__ gamma,
    const float* __restrict__ beta, float* __restrict__ out)
{
  __shared__ float tile[64][65];
  __shared__ float scl[64], sft[64];
  const int tid = threadIdx.x;
  const int s0 = blockIdx.x * 64, d0 = blockIdx.y * 64, b = blockIdx.z;

  if (tid < 64) {
    int d = d0 + tid;
    float mean = s1[d] * (1.f / (float)NBS_);
    float var = s2[d] * (1.f / (float)NBS_) - mean * mean;
    float rstd = rsqrtf(var + EPS_);
    float g = gamma[d];
    scl[tid] = rstd * g;
    sft[tid] = beta[d] - mean * rstd * g;
  }
  __syncthreads();

  const int si = tid >> 2, dc = (tid & 3) * 16;
  const float* row = y + (size_t)(b * S_ + s0 + si) * D_ + d0 + dc;
#pragma unroll
  for (int j = 0; j < 16; ++j)
    tile[si][dc + j] = row[j] * scl[dc + j] + sft[dc + j];
  __syncthreads();

  const int di = tid >> 2, sg = (tid & 3) * 16;
  float* dst = out + (size_t)(b * D_ + d0 + di) * S_ + s0 + sg;
#pragma unroll
  for (int jj = 0; jj < 4; ++jj) {
    float4 p;
    p.x = tile[sg + jj * 4 + 0][di];
    p.y = tile[sg + jj * 4 + 1][di];
    p.z = tile[sg + jj * 4 + 2][di];
    p.w = tile[sg + jj * 4 + 3][di];
    *(float4*)(dst + jj * 4) = p;
  }
}

// ---------------------------------------------------------------------------
extern "C" void kernel_launch(void* const* d_in, const int* in_sizes, int n_in,
                              void* d_out, int out_size, void* d_ws, size_t ws_size,
                              hipStream_t stream)
{
  (void)in_sizes; (void)n_in; (void)out_size; (void)ws_size;
  const float* Q     = (const float*)d_in[0];
  const float* Kin   = (const float*)d_in[1];
  const float* Vin   = (const float*)d_in[2];
  const float* Wq    = (const float*)d_in[3];
  const float* bq    = (const float*)d_in[4];
  const float* Wk    = (const float*)d_in[5];
  const float* bk    = (const float*)d_in[6];
  const float* Wv    = (const float*)d_in[7];
  const float* bv    = (const float*)d_in[8];
  const float* Wo    = (const float*)d_in[9];
  const float* bo    = (const float*)d_in[10];
  const float* gamma = (const float*)d_in[11];
  const float* beta  = (const float*)d_in[12];
  float* out = (float*)d_out;

  char* ws = (char*)d_ws;
  const size_t MB = 1u << 20;
  ushort_t* xb  = (ushort_t*)(ws);
  ushort_t* wtq = (ushort_t*)(ws + 16 * MB);
  ushort_t* wtk = (ushort_t*)(ws + 18 * MB);
  ushort_t* wtv = (ushort_t*)(ws + 20 * MB);
  ushort_t* wto = (ushort_t*)(ws + 22 * MB);
  ushort_t* qb  = (ushort_t*)(ws + 24 * MB);
  ushort_t* kb  = (ushort_t*)(ws + 40 * MB);
  ushort_t* vtb = (ushort_t*)(ws + 56 * MB);
  ushort_t* ao  = (ushort_t*)(ws);
  float*    y   = (float*)(ws + 24 * MB);
  float*    s1  = (float*)(ws + 56 * MB);
  float*    s2  = (float*)(ws + 56 * MB + 4096);

  wtr_k<<<dim3(16, 16), 256, 0, stream>>>(Wq, wtq, 0);
  wtr_k<<<dim3(16, 16), 256, 0, stream>>>(Wk, wtk, 0);
  wtr_k<<<dim3(16, 16), 256, 0, stream>>>(Wv, wtv, 0);
  wtr_k<<<dim3(16, 16), 256, 0, stream>>>(Wo, wto, 1);

  // q pre-scaled by SCALE*log2(e) so attention logits are already exp2-domain
  const float QSC = SCALE_ * 1.44269504088896f;
  cvtx_k<<<4096, 256, 0, stream>>>(Q, xb);
  gemm_proj<<<dim3(64, 8), 256, 0, stream>>>(xb, wtq, bq, qb, QSC);
  cvtx_k<<<4096, 256, 0, stream>>>(Kin, xb);
  gemm_proj<<<dim3(64, 8), 256, 0, stream>>>(xb, wtk, bk, kb, 1.0f);
  cvtx_k<<<4096, 256, 0, stream>>>(Vin, xb);
  gemm_projT<<<dim3(64, 8), 256, 0, stream>>>(xb, wtv, bv, vtb);

  attn_k<<<dim3(16, 16, 4), 256, 0, stream>>>(qb, kb, vtb, ao);
  gemm_oproj<<<dim3(64, 8), 256, 0, stream>>>(ao, wto, bo, Q, y);

  hipMemsetAsync(ws + 56 * MB, 0, 8192, stream);
  stats_k<<<256, 256, 0, stream>>>(y, s1, s2);
  norm_k<<<dim3(32, 16, 4), 256, 0, stream>>>(y, s1, s2, gamma, beta, out);
}